// Round 3
// baseline (1100.283 us; speedup 1.0000x reference)
//
#include <hip/hip_runtime.h>
#include <math.h>

#define TAU 32.0f

// ---------------------------------------------------------------------------
// Kernel 1: MW[n][k] = sum_e M[n%90][e] * W[e][k],  W = (n<90 ? W_topic : W_domain)
// MW is [180][768].  grid = (60 n-tiles of 3 rows) x (3 k-chunks of 256), block=256.
// 90 % 3 == 0 so a 3-row tile never straddles the topic/domain boundary.
// ---------------------------------------------------------------------------
__global__ __launch_bounds__(256) void precompute_mw(
    const float* __restrict__ Wt, const float* __restrict__ Wd,
    const float* __restrict__ dmem, float* __restrict__ MW)
{
    __shared__ float Ml[3 * 768];
    const int nt = blockIdx.x;   // 0..59
    const int kc = blockIdx.y;   // 0..2
    const int n0 = nt * 3;
    const float* __restrict__ W = (n0 < 90) ? Wt : Wd;
    const int m0 = (n0 < 90) ? n0 : n0 - 90;
    for (int idx = threadIdx.x; idx < 3 * 768; idx += 256)
        Ml[idx] = dmem[m0 * 768 + idx];
    __syncthreads();
    const int k = kc * 256 + threadIdx.x;
    float a0 = 0.f, a1 = 0.f, a2 = 0.f;
    #pragma unroll 4
    for (int e = 0; e < 768; ++e) {
        const float w = W[e * 768 + k];          // coalesced across tid
        a0 = fmaf(Ml[e],        w, a0);          // LDS broadcast
        a1 = fmaf(Ml[768 + e],  w, a1);
        a2 = fmaf(Ml[1536 + e], w, a2);
    }
    MW[(n0 + 0) * 768 + k] = a0;
    MW[(n0 + 1) * 768 + k] = a1;
    MW[(n0 + 2) * 768 + k] = a2;
}

// ---------------------------------------------------------------------------
// Kernel 2: fused  raw[B,192] = F @ MW^T  (+ row sumsq)  -> softmax epilogue
// BM=64, BN=192 (180 real + 12 zero pad), BK=32. 256 threads, TM=4 x TN=12.
// LDS: A [64][36], B [192][36] (pad 36 words kills bank conflicts; 16B aligned).
// Epilogue: 2 chunks of 32 rows exchanged through reused LDS.
// ---------------------------------------------------------------------------
#define BM 64
#define BK 32
#define PK 36
#define NPAD 192

__global__ __launch_bounds__(256, 2) void fused_memnet(
    const float* __restrict__ F, const float* __restrict__ MW,
    float* __restrict__ out)
{
    __shared__ alignas(16) float smem[BM * PK + NPAD * PK];  // 9216 floats = 36 KB
    __shared__ float ss[BM];
    float* As = smem;                // [BM][PK]
    float* Bs = smem + BM * PK;      // [NPAD][PK]
    float* Cs = smem;                // [32][196] reuse for epilogue (6272 floats)

    const int tid  = threadIdx.x;
    const int tx   = tid & 15;       // N-direction (strided by 16)
    const int ty   = tid >> 4;       // M-direction (strided by 16)
    const int srow = tid >> 3;       // staging: 0..31
    const int skv  = tid & 7;        // staging: float4 index within BK
    const int row0 = blockIdx.x * BM;

    float acc[4][12];
    #pragma unroll
    for (int i = 0; i < 4; ++i)
        #pragma unroll
        for (int j = 0; j < 12; ++j) acc[i][j] = 0.f;

    float ps0 = 0.f, ps1 = 0.f;      // partial row sum-of-squares

    const float* __restrict__ Fp0 = F + (row0 + srow) * 768 + skv * 4;
    const float* __restrict__ Fp1 = Fp0 + 32 * 768;

    for (int t = 0; t < 24; ++t) {
        const int kb = t * BK;
        // prefetch to registers (global, coalesced 32B/8 lanes per row)
        float4 va0 = *(const float4*)(Fp0 + kb);
        float4 va1 = *(const float4*)(Fp1 + kb);
        float4 vb[6];
        #pragma unroll
        for (int r = 0; r < 6; ++r) {
            const int n = srow + 32 * r;
            if (n < 180) vb[r] = *(const float4*)(MW + n * 768 + kb + skv * 4);
            else         vb[r] = make_float4(0.f, 0.f, 0.f, 0.f);
        }
        __syncthreads();   // previous compute done before overwriting LDS
        *(float4*)(As + srow * PK + skv * 4)        = va0;
        *(float4*)(As + (srow + 32) * PK + skv * 4) = va1;
        #pragma unroll
        for (int r = 0; r < 6; ++r)
            *(float4*)(Bs + (srow + 32 * r) * PK + skv * 4) = vb[r];
        ps0 += va0.x*va0.x + va0.y*va0.y + va0.z*va0.z + va0.w*va0.w;
        ps1 += va1.x*va1.x + va1.y*va1.y + va1.z*va1.z + va1.w*va1.w;
        __syncthreads();

        #pragma unroll
        for (int k4 = 0; k4 < 8; ++k4) {
            float4 a[4], b[12];
            #pragma unroll
            for (int i = 0; i < 4; ++i)
                a[i] = *(const float4*)(As + (ty + 16 * i) * PK + k4 * 4);
            #pragma unroll
            for (int j = 0; j < 12; ++j)
                b[j] = *(const float4*)(Bs + (tx + 16 * j) * PK + k4 * 4);
            #pragma unroll
            for (int i = 0; i < 4; ++i)
                #pragma unroll
                for (int j = 0; j < 12; ++j)
                    acc[i][j] += a[i].x * b[j].x + a[i].y * b[j].y
                               + a[i].z * b[j].z + a[i].w * b[j].w;
        }
    }

    // reduce sumsq across the 8 staging lanes of each row (contiguous, aligned)
    ps0 += __shfl_xor(ps0, 1); ps0 += __shfl_xor(ps0, 2); ps0 += __shfl_xor(ps0, 4);
    ps1 += __shfl_xor(ps1, 1); ps1 += __shfl_xor(ps1, 2); ps1 += __shfl_xor(ps1, 4);
    if (skv == 0) { ss[srow] = ps0; ss[srow + 32] = ps1; }

    // ------------------ epilogue: 2 chunks of 32 rows ------------------
    #pragma unroll
    for (int c = 0; c < 2; ++c) {
        __syncthreads();             // K-loop LDS reads / previous chunk done
        #pragma unroll
        for (int ii = 0; ii < 2; ++ii) {
            const int i = 2 * c + ii;            // compile-time (loops unrolled)
            const int r = ty + 16 * ii;          // row within chunk
            #pragma unroll
            for (int j = 0; j < 12; ++j)
                Cs[r * 196 + tx + 16 * j] = acc[i][j];
        }
        __syncthreads();
        if (tid < 32) {
            const int r = tid;
            const float s = TAU / sqrtf(ss[32 * c + r]);   // TAU / ||f||
            const float* Sr = Cs + r * 196;
            float logit[9];
            #pragma unroll
            for (int d = 0; d < 9; ++d) {
                float v[10];
                float mx = -1e30f;
                #pragma unroll
                for (int m = 0; m < 10; ++m) {
                    v[m] = s * Sr[d * 10 + m];
                    mx = fmaxf(mx, v[m]);
                }
                float den = 0.f, num = 0.f;
                #pragma unroll
                for (int m = 0; m < 10; ++m) {
                    const float e = expf(v[m] - mx);
                    den += e;
                    num = fmaf(e, Sr[90 + d * 10 + m], num);   // raw2, unscaled
                }
                logit[d] = s * num / den;        // TAU * (sep_emb . q_dom)
            }
            float mx2 = -1e30f;
            #pragma unroll
            for (int d = 0; d < 9; ++d) mx2 = fmaxf(mx2, logit[d]);
            float e2[9];
            float den2 = 0.f;
            #pragma unroll
            for (int d = 0; d < 9; ++d) { e2[d] = expf(logit[d] - mx2); den2 += e2[d]; }
            const float inv = 1.f / den2;
            float* op = out + (row0 + 32 * c + r) * 9;
            #pragma unroll
            for (int d = 0; d < 9; ++d) op[d] = e2[d] * inv;
        }
    }
}

// ---------------------------------------------------------------------------
extern "C" void kernel_launch(void* const* d_in, const int* in_sizes, int n_in,
                              void* d_out, int out_size, void* d_ws, size_t ws_size,
                              hipStream_t stream)
{
    const float* feature = (const float*)d_in[0];
    // d_in[1] = category (int64) — unused by the reference computation
    const float* Wt   = (const float*)d_in[2];
    const float* Wd   = (const float*)d_in[3];
    const float* dmem = (const float*)d_in[4];
    float* outp = (float*)d_out;
    float* MW   = (float*)d_ws;          // 180*768 floats = 552,960 bytes

    precompute_mw<<<dim3(60, 3), 256, 0, stream>>>(Wt, Wd, dmem, MW);
    fused_memnet<<<32768 / BM, 256, 0, stream>>>(feature, MW, outp);
}

// Round 4
// 984.491 us; speedup vs baseline: 1.1176x; 1.1176x over previous
//
#include <hip/hip_runtime.h>
#include <math.h>

#define TAU 32.0f

// ---------------------------------------------------------------------------
// Kernel 1: MW[n][k] = sum_e M[n%90][e] * W[e][k],  W = (n<90 ? W_topic : W_domain)
// MW is [180][768].  grid = (60 n-tiles of 3 rows) x (3 k-chunks of 256), block=256.
// ---------------------------------------------------------------------------
__global__ __launch_bounds__(256) void precompute_mw(
    const float* __restrict__ Wt, const float* __restrict__ Wd,
    const float* __restrict__ dmem, float* __restrict__ MW)
{
    __shared__ float Ml[3 * 768];
    const int nt = blockIdx.x;   // 0..59
    const int kc = blockIdx.y;   // 0..2
    const int n0 = nt * 3;
    const float* __restrict__ W = (n0 < 90) ? Wt : Wd;
    const int m0 = (n0 < 90) ? n0 : n0 - 90;
    for (int idx = threadIdx.x; idx < 3 * 768; idx += 256)
        Ml[idx] = dmem[m0 * 768 + idx];
    __syncthreads();
    const int k = kc * 256 + threadIdx.x;
    float a0 = 0.f, a1 = 0.f, a2 = 0.f;
    #pragma unroll 4
    for (int e = 0; e < 768; ++e) {
        const float w = W[e * 768 + k];
        a0 = fmaf(Ml[e],        w, a0);
        a1 = fmaf(Ml[768 + e],  w, a1);
        a2 = fmaf(Ml[1536 + e], w, a2);
    }
    MW[(n0 + 0) * 768 + k] = a0;
    MW[(n0 + 1) * 768 + k] = a1;
    MW[(n0 + 2) * 768 + k] = a2;
}

// ---------------------------------------------------------------------------
// Kernel 2: fused  raw[B,192] = F @ MW^T  (+ row sumsq)  -> softmax epilogue
// 512 threads, BM=64, BN=192, BK=32.  TM=4 x TN=6 -> acc 24 regs/thread.
// Live set ~90 VGPR (acc24 + a16 + b24 + addr) -> fits 128, NO SPILL (the
// round-3 kernel spilled: WRITE_SIZE 2.49 GB of scratch, 1134 us).
// ---------------------------------------------------------------------------
#define BM 64
#define BK 32
#define PK 36
#define NPAD 192

__global__ __launch_bounds__(512, 4) void fused_memnet(
    const float* __restrict__ F, const float* __restrict__ MW,
    float* __restrict__ out)
{
    __shared__ alignas(16) float smem[BM * PK + NPAD * PK];  // 9216 floats = 36 KB
    __shared__ float ss[BM];
    float* As = smem;                // [BM][PK]
    float* Bs = smem + BM * PK;      // [NPAD][PK]
    float* Cs = smem;                // [32][196] reuse for epilogue

    const int tid  = threadIdx.x;
    const int tx   = tid & 31;       // N-direction: cols tx + 32*j, j<6
    const int ty   = tid >> 5;       // M-direction: rows ty + 16*i, i<4 (ty 0..15)
    const int srow = tid >> 3;       // staging row 0..63
    const int skv  = tid & 7;        // staging float4 index within BK
    const int row0 = blockIdx.x * BM;

    float acc[4][6];
    #pragma unroll
    for (int i = 0; i < 4; ++i)
        #pragma unroll
        for (int j = 0; j < 6; ++j) acc[i][j] = 0.f;

    float ps = 0.f;                  // partial row sum-of-squares

    const float* __restrict__ Fp = F + (row0 + srow) * 768 + skv * 4;

    for (int t = 0; t < 24; ++t) {
        const int kb = t * BK;
        float4 va = *(const float4*)(Fp + kb);
        float4 vb[3];
        #pragma unroll
        for (int r = 0; r < 3; ++r) {
            const int n = srow + 64 * r;
            if (n < 180) vb[r] = *(const float4*)(MW + n * 768 + kb + skv * 4);
            else         vb[r] = make_float4(0.f, 0.f, 0.f, 0.f);
        }
        __syncthreads();   // previous compute done before overwriting LDS
        *(float4*)(As + srow * PK + skv * 4) = va;
        #pragma unroll
        for (int r = 0; r < 3; ++r)
            *(float4*)(Bs + (srow + 64 * r) * PK + skv * 4) = vb[r];
        ps += va.x*va.x + va.y*va.y + va.z*va.z + va.w*va.w;
        __syncthreads();

        #pragma unroll
        for (int k4 = 0; k4 < 8; ++k4) {
            float4 a[4], b[6];
            #pragma unroll
            for (int i = 0; i < 4; ++i)
                a[i] = *(const float4*)(As + (ty + 16 * i) * PK + k4 * 4);
            #pragma unroll
            for (int j = 0; j < 6; ++j)
                b[j] = *(const float4*)(Bs + (tx + 32 * j) * PK + k4 * 4);
            #pragma unroll
            for (int i = 0; i < 4; ++i)
                #pragma unroll
                for (int j = 0; j < 6; ++j)
                    acc[i][j] += a[i].x * b[j].x + a[i].y * b[j].y
                               + a[i].z * b[j].z + a[i].w * b[j].w;
        }
    }

    // reduce sumsq across the 8 staging lanes of each row
    ps += __shfl_xor(ps, 1); ps += __shfl_xor(ps, 2); ps += __shfl_xor(ps, 4);
    if (skv == 0) ss[srow] = ps;

    // ------------------ epilogue: 2 chunks of 32 rows ------------------
    #pragma unroll
    for (int c = 0; c < 2; ++c) {
        __syncthreads();             // K-loop LDS reads / previous chunk done
        #pragma unroll
        for (int ii = 0; ii < 2; ++ii) {
            const int i = 2 * c + ii;            // compile-time
            const int r = ty + 16 * ii;          // row within chunk, 0..31
            #pragma unroll
            for (int j = 0; j < 6; ++j)
                Cs[r * 196 + tx + 32 * j] = acc[i][j];
        }
        __syncthreads();
        if (tid < 32) {
            const int r = tid;
            const float s = TAU / sqrtf(ss[32 * c + r]);   // TAU / ||f||
            const float* Sr = Cs + r * 196;
            float logit[9];
            #pragma unroll
            for (int d = 0; d < 9; ++d) {
                float v[10];
                float mx = -1e30f;
                #pragma unroll
                for (int m = 0; m < 10; ++m) {
                    v[m] = s * Sr[d * 10 + m];
                    mx = fmaxf(mx, v[m]);
                }
                float den = 0.f, num = 0.f;
                #pragma unroll
                for (int m = 0; m < 10; ++m) {
                    const float e = expf(v[m] - mx);
                    den += e;
                    num = fmaf(e, Sr[90 + d * 10 + m], num);   // raw2, unscaled
                }
                logit[d] = s * num / den;        // TAU * (sep_emb . q_dom)
            }
            float mx2 = -1e30f;
            #pragma unroll
            for (int d = 0; d < 9; ++d) mx2 = fmaxf(mx2, logit[d]);
            float e2[9];
            float den2 = 0.f;
            #pragma unroll
            for (int d = 0; d < 9; ++d) { e2[d] = expf(logit[d] - mx2); den2 += e2[d]; }
            const float inv = 1.f / den2;
            float* op = out + (row0 + 32 * c + r) * 9;
            #pragma unroll
            for (int d = 0; d < 9; ++d) op[d] = e2[d] * inv;
        }
    }
}

// ---------------------------------------------------------------------------
extern "C" void kernel_launch(void* const* d_in, const int* in_sizes, int n_in,
                              void* d_out, int out_size, void* d_ws, size_t ws_size,
                              hipStream_t stream)
{
    const float* feature = (const float*)d_in[0];
    // d_in[1] = category (int64) — unused by the reference computation
    const float* Wt   = (const float*)d_in[2];
    const float* Wd   = (const float*)d_in[3];
    const float* dmem = (const float*)d_in[4];
    float* outp = (float*)d_out;
    float* MW   = (float*)d_ws;          // 180*768 floats = 552,960 bytes

    precompute_mw<<<dim3(60, 3), 256, 0, stream>>>(Wt, Wd, dmem, MW);
    fused_memnet<<<32768 / BM, 512, 0, stream>>>(feature, MW, outp);
}

// Round 5
// 149.397 us; speedup vs baseline: 7.3648x; 6.5898x over previous
//
#include <hip/hip_runtime.h>
#include <math.h>

#define TAU 32.0f
#define LO_SCALE 2048.0f
#define INV_LO_SCALE (1.0f/2048.0f)

typedef _Float16 f16x8 __attribute__((ext_vector_type(8)));
typedef float    f32x16 __attribute__((ext_vector_type(16)));

// ---------------------------------------------------------------------------
// Kernel 1: MW[n][k] = sum_e M[n%90][e] * W[e][k], n<90 -> W_topic else W_domain.
// Output as f16 hi + f16 scaled-lo (lo*2048) into ws: exactly 180*768*2*2B.
// ---------------------------------------------------------------------------
__global__ __launch_bounds__(256) void precompute_mw(
    const float* __restrict__ Wt, const float* __restrict__ Wd,
    const float* __restrict__ dmem, _Float16* __restrict__ MWhi,
    _Float16* __restrict__ MWlo)
{
    __shared__ float Ml[3 * 768];
    const int nt = blockIdx.x;   // 0..59
    const int kc = blockIdx.y;   // 0..2
    const int n0 = nt * 3;
    const float* __restrict__ W = (n0 < 90) ? Wt : Wd;
    const int m0 = (n0 < 90) ? n0 : n0 - 90;
    for (int idx = threadIdx.x; idx < 3 * 768; idx += 256)
        Ml[idx] = dmem[m0 * 768 + idx];
    __syncthreads();
    const int k = kc * 256 + threadIdx.x;
    float a0 = 0.f, a1 = 0.f, a2 = 0.f;
    #pragma unroll 4
    for (int e = 0; e < 768; ++e) {
        const float w = W[e * 768 + k];
        a0 = fmaf(Ml[e],        w, a0);
        a1 = fmaf(Ml[768 + e],  w, a1);
        a2 = fmaf(Ml[1536 + e], w, a2);
    }
    float v[3] = {a0, a1, a2};
    #pragma unroll
    for (int i = 0; i < 3; ++i) {
        _Float16 h = (_Float16)v[i];
        float lo = (v[i] - (float)h) * LO_SCALE;
        MWhi[(n0 + i) * 768 + k] = h;
        MWlo[(n0 + i) * 768 + k] = (_Float16)lo;
    }
}

// ---------------------------------------------------------------------------
// Kernel 2: raw[64 x 192] = F_tile @ MW^T via mfma_f32_32x32x16_f16 split-GEMM.
// 4 waves: wave w -> rows 32*(w>>1)..+32, cols 96*(w&1)..+96 (3 N-tiles of 32).
// A: fp32 -> f16 hi/lo staged in swizzled LDS. B: f16 frags direct from L2.
// acc1 (hi*hi) + acc2 (cross, x2048) per tile; result = acc1 + acc2/2048.
// Epilogue: raw -> LDS [64][196], 64 threads run the softmax chain.
// ---------------------------------------------------------------------------
__global__ __launch_bounds__(256, 1) void fused_memnet(
    const float* __restrict__ F, const _Float16* __restrict__ MWhi,
    const _Float16* __restrict__ MWlo, float* __restrict__ out)
{
    __shared__ alignas(16) _Float16 AhL[64 * 32];   // 4 KB, swizzled
    __shared__ alignas(16) _Float16 AlL[64 * 32];   // 4 KB, swizzled
    __shared__ float raw[64 * 196];                 // 50.2 KB epilogue scores
    __shared__ float ss[64];

    const int tid  = threadIdx.x;
    const int lane = tid & 63;
    const int wid  = tid >> 6;
    const int wrow = (wid >> 1) * 32;
    const int wcol = (wid & 1) * 96;
    const int row0 = blockIdx.x * 64;

    // ---- staging ids: thread covers (srow, 16B chunk sc) of the A k-window
    const int srow = tid >> 2;        // 0..63
    const int sc   = tid & 3;         // chunk of 8 floats
    const float* __restrict__ Fp = F + (row0 + srow) * 768 + sc * 8;
    const int wb = (srow * 64 + sc * 16) ^ ((srow & 7) << 4);
    char* ahp = (char*)AhL + wb;
    char* alp = (char*)AlL + wb;

    // ---- B fragment base element offsets (row clamped: pad cols 180..191
    //      read row 179 garbage; epilogue only consumes cols 0..179)
    int bofs[3];
    #pragma unroll
    for (int nt = 0; nt < 3; ++nt) {
        int brow = wcol + nt * 32 + (lane & 31);
        if (brow > 179) brow = 179;
        bofs[nt] = brow * 768 + (lane >> 5) * 8;
    }

    // ---- A fragment read addressing
    const int arow = wrow + (lane & 31);
    const int swzA = (arow & 7) << 4;
    const int asel = (lane >> 5) * 16;

    f32x16 acc1[3], acc2[3];
    #pragma unroll
    for (int nt = 0; nt < 3; ++nt)
        #pragma unroll
        for (int r = 0; r < 16; ++r) { acc1[nt][r] = 0.f; acc2[nt][r] = 0.f; }

    float ps = 0.f;
    float4 p0 = *(const float4*)(Fp);
    float4 p1 = *(const float4*)(Fp + 4);

    for (int t = 0; t < 24; ++t) {
        __syncthreads();              // prior LDS reads done before overwrite
        f16x8 h8, l8;
        {
            float xs[8] = {p0.x, p0.y, p0.z, p0.w, p1.x, p1.y, p1.z, p1.w};
            #pragma unroll
            for (int i = 0; i < 8; ++i) {
                float x = xs[i];
                _Float16 h = (_Float16)x;
                h8[i] = h;
                l8[i] = (_Float16)((x - (float)h) * LO_SCALE);
                ps += x * x;
            }
        }
        *(f16x8*)ahp = h8;
        *(f16x8*)alp = l8;
        if (t < 23) {                 // prefetch next k-window (hides HBM)
            p0 = *(const float4*)(Fp + (t + 1) * 32);
            p1 = *(const float4*)(Fp + (t + 1) * 32 + 4);
        }
        __syncthreads();

        const int k0 = t * 32;
        #pragma unroll
        for (int ksub = 0; ksub < 2; ++ksub) {
            const int ao = (arow * 64 + ksub * 32 + asel) ^ swzA;
            f16x8 ah = *(const f16x8*)((const char*)AhL + ao);
            f16x8 al = *(const f16x8*)((const char*)AlL + ao);
            const int kk = k0 + ksub * 16;
            #pragma unroll
            for (int nt = 0; nt < 3; ++nt) {
                f16x8 bh = *(const f16x8*)(MWhi + bofs[nt] + kk);
                f16x8 bl = *(const f16x8*)(MWlo + bofs[nt] + kk);
                acc1[nt] = __builtin_amdgcn_mfma_f32_32x32x16_f16(ah, bh, acc1[nt], 0, 0, 0);
                acc2[nt] = __builtin_amdgcn_mfma_f32_32x32x16_f16(ah, bl, acc2[nt], 0, 0, 0);
                acc2[nt] = __builtin_amdgcn_mfma_f32_32x32x16_f16(al, bh, acc2[nt], 0, 0, 0);
            }
        }
    }

    // ---- row sum-of-squares: 4 staging threads per row
    ps += __shfl_xor(ps, 1);
    ps += __shfl_xor(ps, 2);
    if (sc == 0) ss[srow] = ps;

    // ---- write raw scores to LDS (verified 32x32 C/D layout:
    //      col=lane&31, row=(reg&3)+8*(reg>>2)+4*(lane>>5))
    #pragma unroll
    for (int nt = 0; nt < 3; ++nt) {
        const int cl = wcol + nt * 32 + (lane & 31);
        #pragma unroll
        for (int r = 0; r < 16; ++r) {
            const int rl = wrow + (r & 3) + 8 * (r >> 2) + 4 * (lane >> 5);
            raw[rl * 196 + cl] = acc1[nt][r] + acc2[nt][r] * INV_LO_SCALE;
        }
    }
    __syncthreads();

    // ---- softmax chain, one thread per row
    if (tid < 64) {
        const int r = tid;
        const float s = TAU / sqrtf(ss[r]);       // TAU / ||f||
        const float* Sr = raw + r * 196;
        float logit[9];
        #pragma unroll
        for (int d = 0; d < 9; ++d) {
            float vv[10];
            float mx = -1e30f;
            #pragma unroll
            for (int m = 0; m < 10; ++m) {
                vv[m] = s * Sr[d * 10 + m];
                mx = fmaxf(mx, vv[m]);
            }
            float den = 0.f, num = 0.f;
            #pragma unroll
            for (int m = 0; m < 10; ++m) {
                const float e = expf(vv[m] - mx);
                den += e;
                num = fmaf(e, Sr[90 + d * 10 + m], num);
            }
            logit[d] = s * num / den;             // TAU * (sep_emb . q_dom)
        }
        float mx2 = -1e30f;
        #pragma unroll
        for (int d = 0; d < 9; ++d) mx2 = fmaxf(mx2, logit[d]);
        float e2[9], den2 = 0.f;
        #pragma unroll
        for (int d = 0; d < 9; ++d) { e2[d] = expf(logit[d] - mx2); den2 += e2[d]; }
        const float inv = 1.f / den2;
        float* op = out + (row0 + r) * 9;
        #pragma unroll
        for (int d = 0; d < 9; ++d) op[d] = e2[d] * inv;
    }
}

// ---------------------------------------------------------------------------
extern "C" void kernel_launch(void* const* d_in, const int* in_sizes, int n_in,
                              void* d_out, int out_size, void* d_ws, size_t ws_size,
                              hipStream_t stream)
{
    const float* feature = (const float*)d_in[0];
    // d_in[1] = category (int64) — unused by the reference computation
    const float* Wt   = (const float*)d_in[2];
    const float* Wd   = (const float*)d_in[3];
    const float* dmem = (const float*)d_in[4];
    float* outp = (float*)d_out;
    _Float16* MWhi = (_Float16*)d_ws;            // 180*768 f16
    _Float16* MWlo = MWhi + 180 * 768;           // total 552,960 B (proven fit)

    precompute_mw<<<dim3(60, 3), 256, 0, stream>>>(Wt, Wd, dmem, MWhi, MWlo);
    fused_memnet<<<32768 / 64, 256, 0, stream>>>(feature, MWhi, MWlo, outp);
}